// Round 3
// baseline (267.285 us; speedup 1.0000x reference)
//
#include <hip/hip_runtime.h>

// PositionalEncodingAngle: out[n, j] = sin/cos( |clip(x_n,±45)| / 45^(2*floor(e/2)/1024) )
// where e = j if x_n >= 0 else 1023-j; sin for even j, cos for odd j.
// Pair k = j/2 shares a denominator in both sign branches (index k or 511-k).
// Memory-bound: 256 MiB f32 output, ~45 us write floor at 6 TB/s.

#define PE_D 1024
#define PE_RES 45.0f

// Native clang vector type: required by __builtin_nontemporal_store
// (HIP's float4 is a struct and is rejected).
typedef float vfloat4 __attribute__((ext_vector_type(4)));

__global__ __launch_bounds__(256) void PositionalEncodingAngle_kernel(
    const float* __restrict__ x, float* __restrict__ out) {
    const int n = blockIdx.x;      // position index (0 .. N-1)
    const int tid = threadIdx.x;   // 0..255, covers j = 4*tid .. 4*tid+3 (pairs k=2*tid, 2*tid+1)

    const float v  = x[n];                       // broadcast load, L1-cached
    const float xc = fminf(fmaxf(v, -PE_RES), PE_RES);
    const float a  = fabsf(xc);
    const bool  pos = (xc >= 0.0f);

    // c = log2(45)/512
    const float c = 0.010726275578769f;

    const float k0    = pos ? (float)(2 * tid) : (float)(511 - 2 * tid);
    const float kstep = pos ? 1.0f : -1.0f;

    vfloat4 o;
    {
        const float ang = a * exp2f(-c * k0);          // v_exp_f32
        o.x = __sinf(ang);                              // v_sin_f32
        o.y = __cosf(ang);                              // v_cos_f32
    }
    {
        const float ang = a * exp2f(-c * (k0 + kstep));
        o.z = __sinf(ang);
        o.w = __cosf(ang);
    }

    // Streamed output, never re-read: nontemporal store avoids cache pollution.
    __builtin_nontemporal_store(o, reinterpret_cast<vfloat4*>(out) + (size_t)n * (PE_D / 4) + tid);
}

extern "C" void kernel_launch(void* const* d_in, const int* in_sizes, int n_in,
                              void* d_out, int out_size, void* d_ws, size_t ws_size,
                              hipStream_t stream) {
    const float* x = (const float*)d_in[0];
    float* out = (float*)d_out;
    const int N = out_size / PE_D;  // nbatch * nsources = 65536
    PositionalEncodingAngle_kernel<<<N, 256, 0, stream>>>(x, out);
}

// Round 4
// 264.545 us; speedup vs baseline: 1.0104x; 1.0104x over previous
//
#include <hip/hip_runtime.h>

// PositionalEncodingAngle: out[n, j] = sin/cos( |clip(x_n,±45)| / 45^(2*floor(e/2)/1024) )
// where e = j if x_n >= 0 else 1023-j; sin for even j, cos for odd j.
// Pair k = j/2 uses inv-denom exp2(-c*k) (x>=0) or exp2(-c*(511-k)) (x<0), c = log2(45)/512.
// Memory-bound: 256 MiB f32 output, ~45 us write floor at 6 TB/s.
//
// R3 -> R4: persistent blocks (32 rows per block instead of 1) to kill workgroup
// churn, and the 4 exp2 inverse-denominators hoisted out of the row loop
// (computed once per thread; inner loop = select + 2 mul + 2 sin + 2 cos + store).

#define PE_D 1024
#define PE_RES 45.0f
#define ROWS_PER_BLOCK 32

// Native clang vector type: required by __builtin_nontemporal_store.
typedef float vfloat4 __attribute__((ext_vector_type(4)));

__global__ __launch_bounds__(256) void PositionalEncodingAngle_kernel(
    const float* __restrict__ x, float* __restrict__ out, int N) {
    const int tid = threadIdx.x;                 // 0..255 -> j = 4*tid..4*tid+3 (pairs 2*tid, 2*tid+1)
    const int n0  = blockIdx.x * ROWS_PER_BLOCK;

    // c = log2(45)/512
    const float c = 0.010726275578769f;
    const int   k0 = 2 * tid;

    // Loop-invariant inverse denominators for both sign branches.
    const float e_pos0 = exp2f(-c * (float)(k0));
    const float e_pos1 = exp2f(-c * (float)(k0 + 1));
    const float e_neg0 = exp2f(-c * (float)(511 - k0));
    const float e_neg1 = exp2f(-c * (float)(510 - k0));

    const int n_end = (n0 + ROWS_PER_BLOCK < N) ? n0 + ROWS_PER_BLOCK : N;

    for (int n = n0; n < n_end; ++n) {
        const float v  = x[n];                   // wave-uniform address -> single broadcast load
        const float xc = fminf(fmaxf(v, -PE_RES), PE_RES);
        const float a  = fabsf(xc);
        const bool  pos = (xc >= 0.0f);

        const float d0 = pos ? e_pos0 : e_neg0;
        const float d1 = pos ? e_pos1 : e_neg1;

        const float ang0 = a * d0;
        const float ang1 = a * d1;

        vfloat4 o;
        o.x = __sinf(ang0);
        o.y = __cosf(ang0);
        o.z = __sinf(ang1);
        o.w = __cosf(ang1);

        // Streamed output, never re-read.
        __builtin_nontemporal_store(o, reinterpret_cast<vfloat4*>(out) + (size_t)n * (PE_D / 4) + tid);
    }
}

extern "C" void kernel_launch(void* const* d_in, const int* in_sizes, int n_in,
                              void* d_out, int out_size, void* d_ws, size_t ws_size,
                              hipStream_t stream) {
    const float* x = (const float*)d_in[0];
    float* out = (float*)d_out;
    const int N = out_size / PE_D;               // nbatch * nsources = 65536
    const int grid = (N + ROWS_PER_BLOCK - 1) / ROWS_PER_BLOCK;  // 2048 blocks = 8/CU
    PositionalEncodingAngle_kernel<<<grid, 256, 0, stream>>>(x, out, N);
}

// Round 5
// 253.069 us; speedup vs baseline: 1.0562x; 1.0453x over previous
//
#include <hip/hip_runtime.h>

// PositionalEncodingAngle: out[n, j] = sin/cos( |clip(x_n,±45)| / 45^(2*floor(e/2)/1024) )
// where e = j if x_n >= 0 else 1023-j; sin for even j, cos for odd j.
// Pair k = j/2 uses inv-denom exp2(-c*k) (x>=0) or exp2(-c*(511-k)) (x<0), c = log2(45)/512.
// Memory-bound: 268 MB f32 output, ~42 us write floor at 6.36 TB/s (measured fill rate).
//
// R4 -> R5 A/B: drop __builtin_nontemporal_store (plain store, write-back via L2 —
// same path the 6.36 TB/s harness fill uses) + 2-row unroll for store pipelining.
// If dur_us is neutral (~265), the kernel is at its BW floor and the rest of
// dur_us is harness re-poison fills; if it drops sharply, the nt path was throttling.

#define PE_D 1024
#define PE_RES 45.0f
#define ROWS_PER_BLOCK 32

__global__ __launch_bounds__(256) void PositionalEncodingAngle_kernel(
    const float* __restrict__ x, float* __restrict__ out, int N) {
    const int tid = threadIdx.x;                 // 0..255 -> j = 4*tid..4*tid+3 (pairs 2*tid, 2*tid+1)
    const int n0  = blockIdx.x * ROWS_PER_BLOCK;

    // c = log2(45)/512
    const float c = 0.010726275578769f;
    const int   k0 = 2 * tid;

    // Loop-invariant inverse denominators for both sign branches.
    const float e_pos0 = exp2f(-c * (float)(k0));
    const float e_pos1 = exp2f(-c * (float)(k0 + 1));
    const float e_neg0 = exp2f(-c * (float)(511 - k0));
    const float e_neg1 = exp2f(-c * (float)(510 - k0));

    float4* outv = reinterpret_cast<float4*>(out);

#pragma unroll
    for (int r = 0; r < ROWS_PER_BLOCK; r += 2) {
        const int n = n0 + r;

        const float v0 = x[n];
        const float v1 = x[n + 1];

        const float xc0 = fminf(fmaxf(v0, -PE_RES), PE_RES);
        const float xc1 = fminf(fmaxf(v1, -PE_RES), PE_RES);
        const float a0  = fabsf(xc0);
        const float a1  = fabsf(xc1);

        const float d00 = (xc0 >= 0.0f) ? e_pos0 : e_neg0;
        const float d01 = (xc0 >= 0.0f) ? e_pos1 : e_neg1;
        const float d10 = (xc1 >= 0.0f) ? e_pos0 : e_neg0;
        const float d11 = (xc1 >= 0.0f) ? e_pos1 : e_neg1;

        const float a00 = a0 * d00, a01 = a0 * d01;
        const float a10 = a1 * d10, a11 = a1 * d11;

        float4 o0, o1;
        o0.x = __sinf(a00); o0.y = __cosf(a00); o0.z = __sinf(a01); o0.w = __cosf(a01);
        o1.x = __sinf(a10); o1.y = __cosf(a10); o1.z = __sinf(a11); o1.w = __cosf(a11);

        outv[(size_t)n * (PE_D / 4) + tid]       = o0;
        outv[(size_t)(n + 1) * (PE_D / 4) + tid] = o1;
    }
}

extern "C" void kernel_launch(void* const* d_in, const int* in_sizes, int n_in,
                              void* d_out, int out_size, void* d_ws, size_t ws_size,
                              hipStream_t stream) {
    const float* x = (const float*)d_in[0];
    float* out = (float*)d_out;
    const int N = out_size / PE_D;               // nbatch * nsources = 65536 (multiple of 32)
    const int grid = N / ROWS_PER_BLOCK;         // 2048 blocks = 8/CU
    PositionalEncodingAngle_kernel<<<grid, 256, 0, stream>>>(x, out, N);
}

// Round 6
// 252.652 us; speedup vs baseline: 1.0579x; 1.0016x over previous
//
#include <hip/hip_runtime.h>

// PositionalEncodingAngle: out[n, j] = sin/cos( |clip(x_n,±45)| / 45^(2*floor(e/2)/1024) )
// where e = j if x_n >= 0 else 1023-j; sin for even j, cos for odd j.
// Pair k = j/2 uses inv-denom exp2(-c*k) (x>=0) or exp2(-c*(511-k)) (x<0), c = log2(45)/512.
// Memory-bound: 268 MB f32 output; ~40 us write floor at the 6.7 TB/s measured fill rate.
// Budget: dur_us ~= 201 us harness fills (fixed) + kernel. R5 kernel ~= 52 us.
//
// R5 -> R6: preload all 32 x-values to registers at block start (load latency off
// the store loop), 4-row unroll groups -> 4 independent dwordx4 stores in flight.

#define PE_D 1024
#define PE_RES 45.0f
#define ROWS_PER_BLOCK 32

__global__ __launch_bounds__(256) void PositionalEncodingAngle_kernel(
    const float* __restrict__ x, float* __restrict__ out) {
    const int tid = threadIdx.x;                 // 0..255 -> j = 4*tid..4*tid+3 (pairs 2*tid, 2*tid+1)
    const int n0  = blockIdx.x * ROWS_PER_BLOCK;

    // c = log2(45)/512
    const float c = 0.010726275578769f;
    const int   k0 = 2 * tid;

    // Loop-invariant inverse denominators for both sign branches.
    const float e_pos0 = exp2f(-c * (float)(k0));
    const float e_pos1 = exp2f(-c * (float)(k0 + 1));
    const float e_neg0 = exp2f(-c * (float)(511 - k0));
    const float e_neg1 = exp2f(-c * (float)(510 - k0));

    // Preload the block's 32 positions (wave-uniform scalar loads, L2-hit).
    float xv[ROWS_PER_BLOCK];
#pragma unroll
    for (int r = 0; r < ROWS_PER_BLOCK; ++r) xv[r] = x[n0 + r];

    float4* outv = reinterpret_cast<float4*>(out);

#pragma unroll
    for (int r = 0; r < ROWS_PER_BLOCK; r += 4) {
        float4 o[4];
#pragma unroll
        for (int i = 0; i < 4; ++i) {
            const float xc = fminf(fmaxf(xv[r + i], -PE_RES), PE_RES);
            const float a  = fabsf(xc);
            const bool  p  = (xc >= 0.0f);
            const float a0 = a * (p ? e_pos0 : e_neg0);
            const float a1 = a * (p ? e_pos1 : e_neg1);
            o[i].x = __sinf(a0); o[i].y = __cosf(a0);
            o[i].z = __sinf(a1); o[i].w = __cosf(a1);
        }
#pragma unroll
        for (int i = 0; i < 4; ++i)
            outv[(size_t)(n0 + r + i) * (PE_D / 4) + tid] = o[i];
    }
}

extern "C" void kernel_launch(void* const* d_in, const int* in_sizes, int n_in,
                              void* d_out, int out_size, void* d_ws, size_t ws_size,
                              hipStream_t stream) {
    const float* x = (const float*)d_in[0];
    float* out = (float*)d_out;
    const int N = out_size / PE_D;               // nbatch * nsources = 65536 (multiple of 32)
    const int grid = N / ROWS_PER_BLOCK;         // 2048 blocks = 8/CU
    PositionalEncodingAngle_kernel<<<grid, 256, 0, stream>>>(x, out);
}